// Round 15
// baseline (726.245 us; speedup 1.0000x reference)
//
#include <hip/hip_runtime.h>
#include <hip/hip_bf16.h>
#include <hip/hip_cooperative_groups.h>
#include <stdint.h>

namespace cg = cooperative_groups;
typedef long long ll;
typedef float f32x4 __attribute__((ext_vector_type(4)));
typedef __bf16 bf16x8 __attribute__((ext_vector_type(8)));
typedef __bf16 bf16x4 __attribute__((ext_vector_type(4)));

// ---------------- merged weight prep + Xint zeroing ----------------
__global__ void k_prep(const float* __restrict__ cr_w1, const float* __restrict__ cr_w2,
                       const float* __restrict__ cr_w3, __bf16* __restrict__ Wt1,
                       __bf16* __restrict__ Wt2, __bf16* __restrict__ Wt3,
                       const float* __restrict__ W_trans, __bf16* __restrict__ wth,
                       __bf16* __restrict__ wtl,
                       const float* __restrict__ Wrel0, const float* __restrict__ Wself0,
                       __bf16* __restrict__ wc0h, __bf16* __restrict__ wc0l,
                       const float* __restrict__ Wrel, const float* __restrict__ Wself,
                       __bf16* __restrict__ wc13h, __bf16* __restrict__ wc13l,
                       uint4* __restrict__ XintZ)
{
  __shared__ float t[32][33];
  int b = blockIdx.x; int tid = threadIdx.x;
  if (b < 1024){
    const float* w; __bf16* dst; int C, o;
    if (b < 256){ w=cr_w1; dst=Wt1; C=512; o=b; }
    else if (b < 512){ w=cr_w2; dst=Wt2; C=256; o=b-256; }
    else { w=cr_w3; dst=Wt3; C=256; o=b-512; }
    for (int c=tid; c<C; c+=256){
      const float* src = w + ((size_t)o*C + c)*25;
      float v[25];
      #pragma unroll
      for (int q=0;q<25;q++) v[q] = src[q];
      #pragma unroll
      for (int q=0;q<25;q++) dst[((size_t)o*25 + q)*C + c] = (__bf16)v[q];
    }
  } else if (b < 2560){
    ll idx = (ll)(b-1024)*256 + tid;  // over 768*512
    int r = (int)(idx % 768); int c = (int)(idx / 768);
    float x = W_trans[(ll)r*512 + c];
    __bf16 h = (__bf16)x;
    wth[idx] = h; wtl[idx] = (__bf16)(x - (float)h);
  } else if (b < 6720){
    int Din, Kpad, KD, bx, by;
    const float* wr; const float* ws2; __bf16* hb; __bf16* lb;
    if (b < 3648){
      int b2 = b-2560; bx = b2 % 68; by = b2/68; Din=532; Kpad=2176; KD=544;
      wr = Wrel0; ws2 = Wself0; hb = wc0h; lb = wc0l;
    } else {
      int b3 = b-3648; int l = b3/1024; int r2 = b3%1024; bx = r2%64; by = r2/64;
      Din=512; Kpad=2048; KD=512;
      wr = Wrel + (ll)l*3*512*512; ws2 = Wself + (ll)l*512*512;
      hb = wc13h + (ll)l*512*2048; lb = wc13l + (ll)l*512*2048;
    }
    int k0 = bx*32, o0 = by*32;
    int tx = tid&31, ty = tid>>5;
    for (int j=ty; j<32; j+=8){
      int k = k0 + j; float v = 0.f;
      int r = k / KD, d = k - r*KD;
      if (d < Din && r < 4)
        v = (r<3) ? wr[((ll)(r*Din+d))*512 + o0+tx] : ws2[(ll)d*512 + o0+tx];
      t[j][tx] = v;
    }
    __syncthreads();
    for (int j=ty; j<32; j+=8){
      float x = t[tx][j];
      __bf16 h = (__bf16)x;
      hb[(ll)(o0+j)*Kpad + k0+tx] = h;
      lb[(ll)(o0+j)*Kpad + k0+tx] = (__bf16)(x - (float)h);
    }
  } else {
    ll idx = (ll)(b-6720)*256 + tid;
    if (idx < 475136){
      uint4 z; z.x=0u; z.y=0u; z.z=0u; z.w=0u;
      XintZ[idx] = z;
    }
  }
}

// ---------------- MFMA GEMM (standalone; BN in {32,64,128}) ----------------
template<int SPLIT, int MODE, int BN, int FMAPB>
__global__ __launch_bounds__(512) void gemm_mfma(
    const float* __restrict__ A,
    const __bf16* __restrict__ Bhi, const __bf16* __restrict__ Blo,
    float* __restrict__ Cf, __bf16* __restrict__ Cb,
    int M, int N, int K, ll sA, ll sB, ll sC,
    const float* __restrict__ biasN, const float* __restrict__ biasM,
    const float* __restrict__ gM, const float* __restrict__ beM,
    const float* __restrict__ Hf, const float* __restrict__ Ec,
    const float* __restrict__ CBV)
{
  constexpr int NF = BN/32;
  constexpr int SL = (4096 + BN*64) * (SPLIT?2:1);
  constexpr int REDB = 256*2*NF*16;
  constexpr int LDSB = (2*SL > REDB) ? 2*SL : REDB;
  __shared__ char lds[LDSB];

  int b = blockIdx.z;
  A += sA*b;
  if (!FMAPB){ Bhi += sB*b; if (SPLIT) Blo += sB*b; }

  const int tid = threadIdx.x;
  const int slice = tid>>8;
  const int tl = tid & 255;
  const int w4 = (tid>>6)&3;
  const int grp = tid>>8;
  const int l15 = tid&15, lg=(tid&63)>>4, lg16=lg*16;
  const int wave_m0=(w4>>1)*32, wave_n0=(w4&1)*(BN/2);
  const int m0 = blockIdx.y*64, n0 = blockIdx.x*BN;

  char* sA_H = lds + slice*SL;
  char* sB_H = sA_H + 4096;
  char* sA_L = sB_H + BN*64;
  char* sB_L = sA_L + 4096;

  const int sa_row=tl>>2, sa_c8=tl&3;
  const int sa_byte = sa_row*64 + ((sa_c8*16) ^ (((sa_row>>1)&3)<<4));
  const int gmA = m0 + sa_row;

  int baseA[2], baseB[NF];
  #pragma unroll
  for (int mf=0; mf<2; ++mf){
    int r = wave_m0 + mf*16 + l15;
    baseA[mf] = r*64 + (lg16 ^ (((r>>1)&3)<<4));
  }
  #pragma unroll
  for (int nf=0; nf<NF; ++nf){
    int r = wave_n0 + nf*16 + l15;
    baseB[nf] = r*64 + (lg16 ^ (((r>>1)&3)<<4));
  }

  f32x4 acc[2][NF] = {};

  for (int k0=0; k0<K; k0+=64){
    int kk = k0 + slice*32;
    __syncthreads();
    {
      float f[8] = {0,0,0,0,0,0,0,0};
      if (gmA < M){
        float4 p0 = *reinterpret_cast<const float4*>(A + (ll)gmA*K + kk + sa_c8*8);
        float4 p1 = *reinterpret_cast<const float4*>(A + (ll)gmA*K + kk + sa_c8*8 + 4);
        f[0]=p0.x; f[1]=p0.y; f[2]=p0.z; f[3]=p0.w;
        f[4]=p1.x; f[5]=p1.y; f[6]=p1.z; f[7]=p1.w;
      }
      bf16x8 h, l;
      #pragma unroll
      for (int j=0;j<8;j++){
        h[j] = (__bf16)f[j];
        if (SPLIT) l[j] = (__bf16)(f[j] - (float)h[j]);
      }
      *reinterpret_cast<bf16x8*>(sA_H + sa_byte) = h;
      if (SPLIT) *reinterpret_cast<bf16x8*>(sA_L + sa_byte) = l;
    }
    constexpr int BCH = BN*4;
    #pragma unroll
    for (int i=0;i<(BCH+255)/256;i++){
      int idx = tl + i*256;
      if (idx < BCH){
        int row = idx>>2, c8 = idx&3;
        int gn = n0 + row;
        int byte = row*64 + ((c8*16) ^ (((row>>1)&3)<<4));
        if (FMAPB){
          bf16x8 v = {};
          if (gn < N){
            int pi = gn/22, pj = gn%22;
            const float* hi_ = Hf + ((ll)b*126+pi)*512 + kk + c8*8;
            const float* ei_ = Ec + ((ll)b*22 +pi)*512 + kk + c8*8;
            const float* hj_ = Hf + ((ll)b*126+pj)*512 + kk + c8*8;
            const float* ej_ = Ec + ((ll)b*22 +pj)*512 + kk + c8*8;
            float4 ha = *reinterpret_cast<const float4*>(hi_);
            float4 hb2 = *reinterpret_cast<const float4*>(hi_+4);
            float4 ea = *reinterpret_cast<const float4*>(ei_);
            float4 eb = *reinterpret_cast<const float4*>(ei_+4);
            float4 hc = *reinterpret_cast<const float4*>(hj_);
            float4 hd = *reinterpret_cast<const float4*>(hj_+4);
            float4 ec2 = *reinterpret_cast<const float4*>(ej_);
            float4 ed = *reinterpret_cast<const float4*>(ej_+4);
            float vi[8] = {ha.x+ea.x, ha.y+ea.y, ha.z+ea.z, ha.w+ea.w,
                           hb2.x+eb.x, hb2.y+eb.y, hb2.z+eb.z, hb2.w+eb.w};
            float vj[8] = {hc.x+ec2.x, hc.y+ec2.y, hc.z+ec2.z, hc.w+ec2.w,
                           hd.x+ed.x, hd.y+ed.y, hd.z+ed.z, hd.w+ed.w};
            #pragma unroll
            for (int q=0;q<8;q++) v[q] = (__bf16)(vi[q]*vj[q]);
          }
          *reinterpret_cast<bf16x8*>(sB_H + byte) = v;
        } else {
          bf16x8 v = {};
          if (gn < N) v = *reinterpret_cast<const bf16x8*>(Bhi + (ll)gn*K + kk + c8*8);
          *reinterpret_cast<bf16x8*>(sB_H + byte) = v;
          if (SPLIT){
            bf16x8 vl = {};
            if (gn < N) vl = *reinterpret_cast<const bf16x8*>(Blo + (ll)gn*K + kk + c8*8);
            *reinterpret_cast<bf16x8*>(sB_L + byte) = vl;
          }
        }
      }
    }
    __syncthreads();
    bf16x8 aH[2], bH[NF];
    #pragma unroll
    for (int mf=0; mf<2; ++mf) aH[mf] = *reinterpret_cast<const bf16x8*>(sA_H + baseA[mf]);
    #pragma unroll
    for (int nf=0; nf<NF; ++nf) bH[nf] = *reinterpret_cast<const bf16x8*>(sB_H + baseB[nf]);
    if (SPLIT){
      bf16x8 aL[2], bL[NF];
      #pragma unroll
      for (int mf=0; mf<2; ++mf) aL[mf] = *reinterpret_cast<const bf16x8*>(sA_L + baseA[mf]);
      #pragma unroll
      for (int nf=0; nf<NF; ++nf) bL[nf] = *reinterpret_cast<const bf16x8*>(sB_L + baseB[nf]);
      #pragma unroll
      for (int mf=0; mf<2; ++mf)
        #pragma unroll
        for (int nf=0; nf<NF; ++nf){
          acc[mf][nf] = __builtin_amdgcn_mfma_f32_16x16x32_bf16(aH[mf], bH[nf], acc[mf][nf], 0,0,0);
          acc[mf][nf] = __builtin_amdgcn_mfma_f32_16x16x32_bf16(aH[mf], bL[nf], acc[mf][nf], 0,0,0);
          acc[mf][nf] = __builtin_amdgcn_mfma_f32_16x16x32_bf16(aL[mf], bH[nf], acc[mf][nf], 0,0,0);
        }
    } else {
      #pragma unroll
      for (int mf=0; mf<2; ++mf)
        #pragma unroll
        for (int nf=0; nf<NF; ++nf)
          acc[mf][nf] = __builtin_amdgcn_mfma_f32_16x16x32_bf16(aH[mf], bH[nf], acc[mf][nf], 0,0,0);
    }
  }

  __syncthreads();
  if (grp==1){
    char* rp = lds + (ll)(tid-256)*(2*NF*16);
    #pragma unroll
    for (int mf=0; mf<2; ++mf)
      #pragma unroll
      for (int nf=0; nf<NF; ++nf)
        *reinterpret_cast<f32x4*>(rp + (mf*NF+nf)*16) = acc[mf][nf];
  }
  __syncthreads();
  if (grp!=0) return;
  {
    char* rp = lds + (ll)tid*(2*NF*16);
    #pragma unroll
    for (int mf=0; mf<2; ++mf)
      #pragma unroll
      for (int nf=0; nf<NF; ++nf)
        acc[mf][nf] += *reinterpret_cast<f32x4*>(rp + (mf*NF+nf)*16);
  }

  if (MODE==0 || MODE==1){
    float* C = Cf + sC*b;
    #pragma unroll
    for (int mf=0; mf<2; ++mf){
      int gmb = m0 + wave_m0 + mf*16 + lg*4;
      #pragma unroll
      for (int nf=0; nf<NF; ++nf){
        int gn = n0 + wave_n0 + nf*16 + l15;
        if (gn >= N) continue;
        float bn_ = (MODE==0 && biasN) ? biasN[gn] : 0.f;
        f32x4 a = acc[mf][nf];
        #pragma unroll
        for (int r=0;r<4;r++){
          int gm = gmb + r;
          if (gm < M){
            float v = a[r] + bn_;
            if (MODE==1) v = fmaxf(v, 0.f);
            C[(ll)gm*N + gn] = v;
          }
        }
      }
    }
  } else if (MODE==2){
    __bf16* C = Cb + sC*b;
    #pragma unroll
    for (int mf=0; mf<2; ++mf){
      int gmb = m0 + wave_m0 + mf*16 + lg*4;
      float b0=biasM[gmb], b1=biasM[gmb+1], b2=biasM[gmb+2], b3=biasM[gmb+3];
      float g0=gM[gmb], g1=gM[gmb+1], g2=gM[gmb+2], g3=gM[gmb+3];
      float e0=beM[gmb], e1=beM[gmb+1], e2=beM[gmb+2], e3=beM[gmb+3];
      #pragma unroll
      for (int nf=0; nf<NF; ++nf){
        int gn = n0 + wave_n0 + nf*16 + l15;
        if (gn >= N) continue;
        f32x4 a = acc[mf][nf];
        union { bf16x4 v; uint2 u; } pk;
        pk.v[0] = (__bf16)fmaxf((a[0]+b0)*g0+e0, 0.f);
        pk.v[1] = (__bf16)fmaxf((a[1]+b1)*g1+e1, 0.f);
        pk.v[2] = (__bf16)fmaxf((a[2]+b2)*g2+e2, 0.f);
        pk.v[3] = (__bf16)fmaxf((a[3]+b3)*g3+e3, 0.f);
        *reinterpret_cast<uint2*>(C + (ll)gn*M + gmb) = pk.u;
      }
    }
  } else { // MODE 4
    __bf16* C = Cb + sC*b;
    const float* cb = CBV + (ll)b*512;
    #pragma unroll
    for (int mf=0; mf<2; ++mf){
      int gmb = m0 + wave_m0 + mf*16 + lg*4;
      float b0=biasM[gmb], b1=biasM[gmb+1], b2=biasM[gmb+2], b3=biasM[gmb+3];
      float g0=gM[gmb], g1=gM[gmb+1], g2=gM[gmb+2], g3=gM[gmb+3];
      float e0=beM[gmb], e1=beM[gmb+1], e2=beM[gmb+2], e3=beM[gmb+3];
      float c0=cb[gmb], c1=cb[gmb+1], c2=cb[gmb+2], c3=cb[gmb+3];
      #pragma unroll
      for (int nf=0; nf<NF; ++nf){
        int gn = n0 + wave_n0 + nf*16 + l15;
        if (gn >= N) continue;
        f32x4 a = acc[mf][nf];
        int pi = gn/22, pj = gn%22;
        float4 hi4 = *reinterpret_cast<const float4*>(Hf + ((ll)b*126+pi)*512 + gmb);
        float4 ei4 = *reinterpret_cast<const float4*>(Ec + ((ll)b*22 +pi)*512 + gmb);
        float4 hj4 = *reinterpret_cast<const float4*>(Hf + ((ll)b*126+pj)*512 + gmb);
        float4 ej4 = *reinterpret_cast<const float4*>(Ec + ((ll)b*22 +pj)*512 + gmb);
        float fm0 = (hi4.x+ei4.x)*(hj4.x+ej4.x);
        float fm1 = (hi4.y+ei4.y)*(hj4.y+ej4.y);
        float fm2 = (hi4.z+ei4.z)*(hj4.z+ej4.z);
        float fm3 = (hi4.w+ei4.w)*(hj4.w+ej4.w);
        float s0 = (a[0]+b0)*g0+e0 + c0;
        float s1 = (a[1]+b1)*g1+e1 + c1;
        float s2 = (a[2]+b2)*g2+e2 + c2;
        float s3 = (a[3]+b3)*g3+e3 + c3;
        union { bf16x4 v; uint2 u; } pk;
        pk.v[0] = (__bf16)(fm0 / (1.f + expf(-s0)));
        pk.v[1] = (__bf16)(fm1 / (1.f + expf(-s1)));
        pk.v[2] = (__bf16)(fm2 / (1.f + expf(-s2)));
        pk.v[3] = (__bf16)(fm3 / (1.f + expf(-s3)));
        int py = gn/22, px = gn%22;
        int e = (py+2)*32 + px + 2;
        *reinterpret_cast<uint2*>(C + (ll)e*512 + gmb) = pk.u;
      }
    }
  }
}

// ---------------- cooperative RGCN chain: 4x (buildX + GEMM) in one launch ----------------
__device__ __forceinline__ void buildX_phase(const float* __restrict__ h,
                                             float* __restrict__ X, int Din, int KD){
  const float inv1 = 1.f/(1.f+1e-5f), inv3 = 1.f/(3.f+1e-5f), inv4 = 1.f/(4.f+1e-5f);
  int total = 504*KD;
  for (int idx = blockIdx.x*512 + threadIdx.x; idx < total; idx += 128*512){
    int row = idx / KD;
    int d = idx - row*KD;
    int n = row/126, i = row - n*126;
    const float* hb = h + (ll)n*126*Din;
    float m0v=0.f, m1v=0.f, m2v=0.f, hh=0.f;
    if (d < Din){
      if (i < 22){
        int base = 22 + i*4;
        float s = hb[(ll)(base+0)*Din+d] + hb[(ll)(base+1)*Din+d]
                + hb[(ll)(base+2)*Din+d] + hb[(ll)(base+3)*Din+d];
        m0v = s * inv4;
      } else if (i < 110){
        int em = i-22, e = em>>2, base = 22+(e<<2);
        m0v = hb[(ll)e*Din+d] * inv1;
        float s1 = 0.f;
        #pragma unroll
        for (int m2=0;m2<4;m2++) if (base+m2 != i) s1 += hb[(ll)(base+m2)*Din+d];
        m1v = s1 * inv3;
        m2v = hb[(ll)(110+(em&15))*Din+d] * inv1;
      } else {
        int li0 = i-110;
        int cnt = (li0<8)?6:5;
        float s = 0.f;
        for (int t2=0;t2<cnt;t2++) s += hb[(ll)(22+li0+16*t2)*Din+d];
        m2v = s / ((float)cnt + 1e-5f);
      }
      hh = hb[(ll)i*Din+d];
    }
    ll rowoff = (ll)row*4*KD;
    X[rowoff + 0*KD + d] = m0v;
    X[rowoff + 1*KD + d] = m1v;
    X[rowoff + 2*KD + d] = m2v;
    X[rowoff + 3*KD + d] = hh;
  }
}

// GEMM phase: M=504, N=512, BN=32, SPLIT A in staging; grid 128 = 16(N) x 8(M)
__device__ __forceinline__ void rgcn_gemm_phase(
    const float* __restrict__ A, const __bf16* __restrict__ Bhi,
    const __bf16* __restrict__ Blo, float* __restrict__ C, int K, char* lds)
{
  constexpr int BN=32, NF=1, SL=(4096+BN*64)*2;
  const int M=504, N=512;
  const int tid = threadIdx.x;
  const int slice = tid>>8;
  const int tl = tid & 255;
  const int w4 = (tid>>6)&3;
  const int grp = tid>>8;
  const int l15 = tid&15, lg=(tid&63)>>4, lg16=lg*16;
  const int wave_m0=(w4>>1)*32, wave_n0=(w4&1)*(BN/2);
  const int m0 = (blockIdx.x>>4)*64, n0 = (blockIdx.x&15)*BN;

  char* sA_H = lds + slice*SL;
  char* sB_H = sA_H + 4096;
  char* sA_L = sB_H + BN*64;
  char* sB_L = sA_L + 4096;

  const int sa_row=tl>>2, sa_c8=tl&3;
  const int sa_byte = sa_row*64 + ((sa_c8*16) ^ (((sa_row>>1)&3)<<4));
  const int gmA = m0 + sa_row;

  int baseA[2], baseB[NF];
  #pragma unroll
  for (int mf=0; mf<2; ++mf){
    int r = wave_m0 + mf*16 + l15;
    baseA[mf] = r*64 + (lg16 ^ (((r>>1)&3)<<4));
  }
  #pragma unroll
  for (int nf=0; nf<NF; ++nf){
    int r = wave_n0 + nf*16 + l15;
    baseB[nf] = r*64 + (lg16 ^ (((r>>1)&3)<<4));
  }

  f32x4 acc[2][NF] = {};

  for (int k0=0; k0<K; k0+=64){
    int kk = k0 + slice*32;
    __syncthreads();
    {
      float f[8] = {0,0,0,0,0,0,0,0};
      if (gmA < M){
        float4 p0 = *reinterpret_cast<const float4*>(A + (ll)gmA*K + kk + sa_c8*8);
        float4 p1 = *reinterpret_cast<const float4*>(A + (ll)gmA*K + kk + sa_c8*8 + 4);
        f[0]=p0.x; f[1]=p0.y; f[2]=p0.z; f[3]=p0.w;
        f[4]=p1.x; f[5]=p1.y; f[6]=p1.z; f[7]=p1.w;
      }
      bf16x8 h, l;
      #pragma unroll
      for (int j=0;j<8;j++){
        h[j] = (__bf16)f[j];
        l[j] = (__bf16)(f[j] - (float)h[j]);
      }
      *reinterpret_cast<bf16x8*>(sA_H + sa_byte) = h;
      *reinterpret_cast<bf16x8*>(sA_L + sa_byte) = l;
    }
    if (tl < BN*4){
      int row = tl>>2, c8 = tl&3;
      int gn = n0 + row;
      int byte = row*64 + ((c8*16) ^ (((row>>1)&3)<<4));
      bf16x8 v = *reinterpret_cast<const bf16x8*>(Bhi + (ll)gn*K + kk + c8*8);
      bf16x8 vl = *reinterpret_cast<const bf16x8*>(Blo + (ll)gn*K + kk + c8*8);
      *reinterpret_cast<bf16x8*>(sB_H + byte) = v;
      *reinterpret_cast<bf16x8*>(sB_L + byte) = vl;
    }
    __syncthreads();
    bf16x8 aH[2], bH[NF], aL[2], bL[NF];
    #pragma unroll
    for (int mf=0; mf<2; ++mf){
      aH[mf] = *reinterpret_cast<const bf16x8*>(sA_H + baseA[mf]);
      aL[mf] = *reinterpret_cast<const bf16x8*>(sA_L + baseA[mf]);
    }
    #pragma unroll
    for (int nf=0; nf<NF; ++nf){
      bH[nf] = *reinterpret_cast<const bf16x8*>(sB_H + baseB[nf]);
      bL[nf] = *reinterpret_cast<const bf16x8*>(sB_L + baseB[nf]);
    }
    #pragma unroll
    for (int mf=0; mf<2; ++mf)
      #pragma unroll
      for (int nf=0; nf<NF; ++nf){
        acc[mf][nf] = __builtin_amdgcn_mfma_f32_16x16x32_bf16(aH[mf], bH[nf], acc[mf][nf], 0,0,0);
        acc[mf][nf] = __builtin_amdgcn_mfma_f32_16x16x32_bf16(aH[mf], bL[nf], acc[mf][nf], 0,0,0);
        acc[mf][nf] = __builtin_amdgcn_mfma_f32_16x16x32_bf16(aL[mf], bH[nf], acc[mf][nf], 0,0,0);
      }
  }

  __syncthreads();
  if (grp==1){
    char* rp = lds + (ll)(tid-256)*(2*NF*16);
    #pragma unroll
    for (int mf=0; mf<2; ++mf)
      #pragma unroll
      for (int nf=0; nf<NF; ++nf)
        *reinterpret_cast<f32x4*>(rp + (mf*NF+nf)*16) = acc[mf][nf];
  }
  __syncthreads();
  if (grp==0){
    char* rp = lds + (ll)tid*(2*NF*16);
    #pragma unroll
    for (int mf=0; mf<2; ++mf)
      #pragma unroll
      for (int nf=0; nf<NF; ++nf)
        acc[mf][nf] += *reinterpret_cast<f32x4*>(rp + (mf*NF+nf)*16);
    #pragma unroll
    for (int mf=0; mf<2; ++mf){
      int gmb = m0 + wave_m0 + mf*16 + lg*4;
      #pragma unroll
      for (int nf=0; nf<NF; ++nf){
        int gn = n0 + wave_n0 + nf*16 + l15;
        f32x4 a = acc[mf][nf];
        #pragma unroll
        for (int r=0;r<4;r++){
          int gm = gmb + r;
          if (gm < M) C[(ll)gm*N + gn] = fmaxf(a[r], 0.f);
        }
      }
    }
  }
}

__global__ __launch_bounds__(512) void rgcn_coop(
    const float* __restrict__ h0, float* __restrict__ X,
    const __bf16* __restrict__ wc0h, const __bf16* __restrict__ wc0l,
    const __bf16* __restrict__ wc13h, const __bf16* __restrict__ wc13l,
    float* __restrict__ hA, float* __restrict__ hB)
{
  cg::grid_group grid = cg::this_grid();
  __shared__ char lds[24576];
  for (int layer=0; layer<4; ++layer){
    const int Din = (layer==0)?532:512;
    const int KD  = (layer==0)?544:512;
    const int K   = 4*KD;
    const float* hin = (layer==0)? h0 : ((layer&1)? hA : hB);
    float* hout = (layer&1)? hB : hA;
    const __bf16* Bh = (layer==0)? wc0h : (wc13h + (ll)(layer-1)*512*2048);
    const __bf16* Bl = (layer==0)? wc0l : (wc13l + (ll)(layer-1)*512*2048);
    buildX_phase(hin, X, Din, KD);
    grid.sync();
    rgcn_gemm_phase(X, Bh, Bl, hout, K, lds);
    grid.sync();
  }
}

// ---------------- MFMA bf16 5x5 conv (LDS-staged, o-tile templated) ----------------
template<int CIN, int OCHT, int OT, bool FINAL>
__global__ __launch_bounds__(256) void conv5_mfma(
    const __bf16* __restrict__ Xg, const __bf16* __restrict__ Wt,
    const float* __restrict__ bias, __bf16* __restrict__ Xout,
    float* __restrict__ outF)
{
  constexpr int OF = OT/32;
  constexpr int WCH = OT*4;
  __shared__ bf16x8 Xs8[272*32/8];
  __shared__ bf16x8 Ws8[5*OT*32/8];
  char* xs = (char*)Xs8;
  char* wsm = (char*)Ws8;

  const int tid = threadIdx.x;
  const int l = tid & 63;
  const int l15 = l & 15, lg = l >> 4, lg16 = (l>>4)*16;
  const int w = tid >> 6;
  const int wave_o0 = (w>>1)*(OT/2);
  const int wave_p0 = (w&1)*64;
  const int b = blockIdx.z;
  const int p0 = blockIdx.x*128;
  const int o0 = blockIdx.y*OT;

  int baseA[OF];
  #pragma unroll
  for (int of=0; of<OF; ++of){
    int orow = wave_o0 + of*16 + l15;
    baseA[of] = orow*64 + (lg16 ^ (((orow>>1)&3)<<4));
  }
  int pl[4];
  #pragma unroll
  for (int pf=0; pf<4; ++pf) pl[pf] = wave_p0 + pf*16 + l15;

  f32x4 acc[OF][4] = {};

  const int NCB = CIN/32;
  for (int cblk=0; cblk<NCB; ++cblk){
    __syncthreads();
    #pragma unroll
    for (int i=0;i<5;i++){
      int idx = tid + i*256;
      if (idx < 1088){
        int e = idx>>2, c8 = idx&3;
        const __bf16* g = Xg + ((size_t)(b*928 + p0 + e))*CIN + cblk*32 + c8*8;
        bf16x8 v = *reinterpret_cast<const bf16x8*>(g);
        int byte = e*64 + ((c8*16) ^ (((e>>1)&3)<<4));
        *reinterpret_cast<bf16x8*>(xs + byte) = v;
      }
    }
    for (int g5=0; g5<5; ++g5){
      if (g5>0) __syncthreads();
      #pragma unroll
      for (int i=0;i<(5*WCH+255)/256;i++){
        int idx = tid + i*256;
        if (idx < 5*WCH){
          int tapL = idx/WCH, r = idx%WCH;
          int o = r>>2, c8 = r&3;
          const __bf16* g = Wt + ((size_t)(o0+o)*25 + (g5*5+tapL))*CIN + cblk*32 + c8*8;
          bf16x8 v = *reinterpret_cast<const bf16x8*>(g);
          int byte = tapL*(OT*64) + o*64 + ((c8*16) ^ (((o>>1)&3)<<4));
          *reinterpret_cast<bf16x8*>(wsm + byte) = v;
        }
      }
      __syncthreads();
      #pragma unroll
      for (int tapL=0; tapL<5; ++tapL){
        bf16x8 a[OF];
        #pragma unroll
        for (int of=0; of<OF; ++of)
          a[of] = *reinterpret_cast<const bf16x8*>(wsm + tapL*(OT*64) + baseA[of]);
        int koff = g5*32 + tapL;
        #pragma unroll
        for (int pf=0; pf<4; ++pf){
          int e = pl[pf] + koff;
          bf16x8 bv = *reinterpret_cast<const bf16x8*>(xs + e*64 + (lg16 ^ (((e>>1)&3)<<4)));
          #pragma unroll
          for (int of=0; of<OF; ++of)
            acc[of][pf] = __builtin_amdgcn_mfma_f32_16x16x32_bf16(a[of], bv, acc[of][pf], 0,0,0);
        }
      }
    }
  }

  #pragma unroll
  for (int of=0; of<OF; ++of){
    int og = o0 + wave_o0 + of*16 + lg*4;
    float b0 = bias[og], b1 = bias[og+1], b2 = bias[og+2], b3 = bias[og+3];
    #pragma unroll
    for (int pf=0; pf<4; ++pf){
      int p = p0 + pl[pf];
      int py = p>>5, px = p&31;
      if (py>=22 || px>=22) continue;
      f32x4 a = acc[of][pf];
      float v0 = fmaxf(a[0]+b0, 0.f), v1 = fmaxf(a[1]+b1, 0.f);
      float v2 = fmaxf(a[2]+b2, 0.f), v3 = fmaxf(a[3]+b3, 0.f);
      if (FINAL){
        size_t base = ((size_t)b*OCHT + og)*484 + py*22 + px;
        outF[base] = v0; outF[base+484] = v1; outF[base+968] = v2; outF[base+1452] = v3;
      } else {
        union { bf16x4 v; uint2 u; } pk;
        pk.v[0] = (__bf16)v0; pk.v[1] = (__bf16)v1; pk.v[2] = (__bf16)v2; pk.v[3] = (__bf16)v3;
        int e = p + 66;
        *reinterpret_cast<uint2*>(Xout + ((size_t)(b*928 + e))*OCHT + og) = pk.u;
      }
    }
  }
}

// ---------------- merged gather: nodes + ea + seqT ----------------
__global__ void k_gather(const float* __restrict__ seq, const float* __restrict__ att,
                         const int* __restrict__ midx, const int* __restrict__ ls_,
                         const float* __restrict__ te, float* __restrict__ h0,
                         float* __restrict__ ea, __bf16* __restrict__ sqTh,
                         __bf16* __restrict__ sqTl)
{
  __shared__ float part[32][8];
  __shared__ float wv[32];
  __shared__ float vals[1024];
  __shared__ float red[256];
  __shared__ float tt2[32][33];
  int b = blockIdx.x; int t = threadIdx.x;
  if (b < 88){
    int n = b/22, e = b%22;
    int rows[4];
    #pragma unroll
    for (int m=0;m<4;m++) rows[m] = midx[(n*22+e)*4+m];
    for (int d=t; d<512; d+=256){
      float v[4]; float mx = -1e30f;
      #pragma unroll
      for (int m=0;m<4;m++){
        v[m] = seq[((ll)n*1024+rows[m])*512 + d];
        h0[((ll)n*126+22+e*4+m)*532 + d] = v[m];
        mx = fmaxf(mx, v[m]);
      }
      float s = 0.f;
      #pragma unroll
      for (int m=0;m<4;m++) s += expf(v[m]-mx);
      h0[((ll)n*126+e)*532 + d] = mx + logf(s);
    }
  } else if (b < 152){
    int bb = b-88;
    int n = bb/16, l = bb%16;
    int ls = ls_[n*16+l];
    int tt = t>>3, lane = t&7;
    float acc = 0.f;
    for (int i=lane; i<384; i+=8){
      int h = i>>5, s = i&31;
      acc += att[((ll)(n*12+h)*1024 + ls+s)*1024 + (ls+tt)];
    }
    part[tt][lane] = acc; __syncthreads();
    if (lane==0){
      float s2=0.f;
      #pragma unroll
      for (int q=0;q<8;q++) s2 += part[tt][q];
      wv[tt] = s2*(1.f/12.f);
    }
    __syncthreads();
    for (int d=t; d<512; d+=256){
      float a2 = 0.f;
      for (int tk=0;tk<32;tk++) a2 += wv[tk]*seq[((ll)n*1024+ls+tk)*512 + d];
      h0[((ll)n*126+110+l)*532 + d] = a2*(1.f/32.f);
    }
  } else if (b < 192){
    int idx = (b-152)*256 + t;
    if (idx < 4*126*20){
      int q = idx%20; int i = (idx/20)%126; int n = idx/(20*126);
      int ty = (i<22)?0:((i<110)?1:2);
      h0[((ll)n*126+i)*532 + 512 + q] = te[ty*20+q];
    }
  } else if (b < 280){
    int bb = b-192;
    int n = bb/22, e = bb%22;
    int rows[4];
    #pragma unroll
    for (int m=0;m<4;m++) rows[m] = midx[(n*22+e)*4+m];
    float local = 0.f;
    for (int c=t; c<1024; c+=256){
      float acc = 0.f;
      #pragma unroll
      for (int m=0;m<4;m++){
        const float* base = att + ((ll)n*12*1024 + rows[m])*1024 + c;
        #pragma unroll
        for (int h=0;h<12;h++) acc += base[(ll)h*1048576];
      }
      acc *= (1.f/48.f);
      vals[c] = acc; local += acc;
    }
    red[t] = local; __syncthreads();
    for (int s=128;s>0;s>>=1){ if (t<s) red[t]+=red[t+s]; __syncthreads(); }
    float denom = red[0] + 1e-5f;
    for (int c=t; c<1024; c+=256) ea[((ll)bb)*1024 + c] = vals[c]/denom;
  } else {
    int b2 = b-280;
    int n = b2>>9; int rem = b2&511;
    int r0 = (rem&31)*32, c0 = (rem>>5)*32;
    int tx = t&31, ty = t>>5;
    for (int j=ty; j<32; j+=8)
      tt2[j][tx] = seq[((ll)n*1024 + r0+j)*512 + c0+tx];
    __syncthreads();
    for (int j=ty; j<32; j+=8){
      float x = tt2[tx][j];
      __bf16 h = (__bf16)x;
      ll o = ((ll)n*512 + c0+j)*1024 + r0+tx;
      sqTh[o] = h; sqTl[o] = (__bf16)(x - (float)h);
    }
  }
}

// ---------------- pooled channel-SE MLP ----------------
__global__ void k_poolcb(const float* __restrict__ hfin, const float* __restrict__ ectx,
                         const float* __restrict__ w1, const float* __restrict__ b1,
                         const float* __restrict__ g1, const float* __restrict__ be1,
                         const float* __restrict__ w2, const float* __restrict__ b2,
                         const float* __restrict__ g2, const float* __restrict__ be2,
                         float* __restrict__ cb){
  __shared__ float ps[512], t1[256];
  int n = blockIdx.x; int t = threadIdx.x;
  for (int c=t; c<512; c+=256){
    float s = 0.f;
    for (int i=0;i<22;i++)
      s += hfin[((ll)n*126+i)*512 + c] + ectx[((ll)n*22+i)*512 + c];
    ps[c] = s*s*(1.f/484.f);
  }
  __syncthreads();
  {
    float acc = 0.f;
    for (int c=0;c<512;c++) acc += w1[t*512+c]*ps[c];
    float v = g1[t]*(acc+b1[t]) + be1[t];
    t1[t] = fmaxf(v, 0.f);
  }
  __syncthreads();
  for (int o=t; o<512; o+=256){
    float acc = 0.f;
    for (int c=0;c<256;c++) acc += w2[o*256+c]*t1[c];
    cb[n*512+o] = g2[o]*(acc+b2[o]) + be2[o];
  }
}

// ---------------- launcher ----------------
extern "C" void kernel_launch(void* const* d_in, const int* in_sizes, int n_in,
                              void* d_out, int out_size, void* d_ws, size_t ws_size,
                              hipStream_t stream)
{
  (void)in_sizes; (void)n_in; (void)out_size; (void)ws_size;
  const float* seqout   = (const float*)d_in[0];
  const float* att      = (const float*)d_in[1];
  const float* W_trans  = (const float*)d_in[2];
  const float* b_trans  = (const float*)d_in[3];
  const float* type_emb = (const float*)d_in[4];
  const float* Wrel0    = (const float*)d_in[5];
  const float* Wself0   = (const float*)d_in[6];
  const float* Wrel     = (const float*)d_in[7];
  const float* Wself    = (const float*)d_in[8];
  const float* fs_w1    = (const float*)d_in[9];
  const float* fs_b1    = (const float*)d_in[10];
  const float* fs_g1    = (const float*)d_in[11];
  const float* fs_be1   = (const float*)d_in[12];
  const float* fs_w2    = (const float*)d_in[13];
  const float* fs_b2    = (const float*)d_in[14];
  const float* fs_g2    = (const float*)d_in[15];
  const float* fs_be2   = (const float*)d_in[16];
  const float* fc_w1    = (const float*)d_in[17];
  const float* fc_b1    = (const float*)d_in[18];
  const float* fc_g1    = (const float*)d_in[19];
  const float* fc_be1   = (const float*)d_in[20];
  const float* fc_w2    = (const float*)d_in[21];
  const float* fc_b2    = (const float*)d_in[22];
  const float* fc_g2    = (const float*)d_in[23];
  const float* fc_be2   = (const float*)d_in[24];
  const float* cr_w1    = (const float*)d_in[25];
  const float* cr_b1    = (const float*)d_in[26];
  const float* cr_w2    = (const float*)d_in[27];
  const float* cr_b2    = (const float*)d_in[28];
  const float* cr_w3    = (const float*)d_in[29];
  const float* cr_b3    = (const float*)d_in[30];
  const int*   midx     = (const int*)d_in[31];
  const int*   lstart   = (const int*)d_in[32];
  float* out            = (float*)d_out;

  char* wsb = (char*)d_ws;
  size_t off = 0;
  auto allocB = [&](size_t nbytes)->char*{ char* p = wsb + off; off += (nbytes + 63) & ~(size_t)63; return p; };
  float* seq   = (float*)allocB((size_t)4096*512*4);
  float* h0    = (float*)allocB((size_t)504*532*4);
  float* ea    = (float*)allocB((size_t)88*1024*4);
  float* ectx  = (float*)allocB((size_t)88*512*4);
  float* X     = (float*)allocB((size_t)504*2176*4);
  float* hA    = (float*)allocB((size_t)504*512*4);
  float* hB    = (float*)allocB((size_t)504*512*4);
  float* cbv   = (float*)allocB(2048*4);
  __bf16* wth  = (__bf16*)allocB((size_t)512*768*2);
  __bf16* wtl  = (__bf16*)allocB((size_t)512*768*2);
  __bf16* sqTh = (__bf16*)allocB((size_t)4*512*1024*2);
  __bf16* sqTl = (__bf16*)allocB((size_t)4*512*1024*2);
  __bf16* wc0h = (__bf16*)allocB((size_t)512*2176*2);
  __bf16* wc0l = (__bf16*)allocB((size_t)512*2176*2);
  __bf16* wc13h= (__bf16*)allocB((size_t)3*512*2048*2);
  __bf16* wc13l= (__bf16*)allocB((size_t)3*512*2048*2);
  __bf16* s1bT = (__bf16*)allocB((size_t)4*484*256*2);
  __bf16* Xint1 = (__bf16*)allocB((size_t)4*928*512*2);
  __bf16* Xint2 = (__bf16*)allocB((size_t)4*928*256*2);
  __bf16* Xint3 = (__bf16*)allocB((size_t)4*928*256*2);
  __bf16* Wt1   = (__bf16*)allocB((size_t)256*25*512*2);
  __bf16* Wt2   = (__bf16*)allocB((size_t)256*25*256*2);
  __bf16* Wt3   = (__bf16*)allocB((size_t)512*25*256*2);

  // weight prep + Xint zeroing, one dispatch
  k_prep<<<8576,256,0,stream>>>(cr_w1, cr_w2, cr_w3, Wt1, Wt2, Wt3,
                                W_trans, wth, wtl,
                                Wrel0, Wself0, wc0h, wc0l,
                                Wrel, Wself, wc13h, wc13l,
                                reinterpret_cast<uint4*>(Xint1));

  // seq = seqout @ W_trans + b_trans
  gemm_mfma<1,0,128,0><<<dim3(4,64,1),512,0,stream>>>(seqout, wth, wtl, seq, nullptr,
      4096,512,768, 0,0,0, b_trans,nullptr,nullptr,nullptr, nullptr,nullptr,nullptr);
  // node features + ea + seqT (one dispatch)
  k_gather<<<2328,256,0,stream>>>(seq, att, midx, lstart, type_emb, h0, ea, sqTh, sqTl);
  // e_ctx = ea @ seq
  gemm_mfma<1,0,64,0><<<dim3(8,1,4),512,0,stream>>>(ea, sqTh, sqTl, ectx, nullptr,
      22,512,1024, (ll)22*1024, (ll)512*1024, (ll)22*512,
      nullptr,nullptr,nullptr,nullptr, nullptr,nullptr,nullptr);
  // RGCN chain: 4x (buildX + GEMM) in ONE cooperative launch
  {
    void* args[8];
    args[0]=(void*)&h0;  args[1]=(void*)&X;
    args[2]=(void*)&wc0h; args[3]=(void*)&wc0l;
    args[4]=(void*)&wc13h; args[5]=(void*)&wc13l;
    args[6]=(void*)&hA;  args[7]=(void*)&hB;
    (void)hipLaunchCooperativeKernel(reinterpret_cast<void*>(rgcn_coop),
                                     dim3(128), dim3(512), args, 0, stream);
  }
  float* hcur = hB;   // final layer output
  // pooled channel-SE MLP
  k_poolcb<<<4,256,0,stream>>>(hcur, ectx, fc_w1, fc_b1, fc_g1, fc_be1,
                               fc_w2, fc_b2, fc_g2, fc_be2, cbv);
  // SE spatial 1 (B = virtual fmap from hcur/ectx)
  gemm_mfma<0,2,64,1><<<dim3(8,4,4),512,0,stream>>>(fs_w1, nullptr, nullptr, nullptr, s1bT,
      256,484,512, 0, 0, (ll)484*256,
      nullptr, fs_b1, fs_g1, fs_be1, hcur, ectx, nullptr);
  // SE spatial 2 fused gate -> Xint1
  gemm_mfma<0,4,64,0><<<dim3(8,8,4),512,0,stream>>>(fs_w2, s1bT, nullptr, nullptr, Xint1,
      512,484,256, 0, (ll)484*256, (ll)928*512,
      nullptr, fs_b2, fs_g2, fs_be2, hcur, ectx, cbv);
  // conv stack (r13 shapes, OT=64)
  conv5_mfma<512,256,64,false><<<dim3(6,4,4),256,0,stream>>>(Xint1, Wt1, cr_b1, Xint2, nullptr);
  conv5_mfma<256,256,64,false><<<dim3(6,4,4),256,0,stream>>>(Xint2, Wt2, cr_b2, Xint3, nullptr);
  conv5_mfma<256,512,64,true ><<<dim3(6,8,4),256,0,stream>>>(Xint3, Wt3, cr_b3, nullptr, out);
}

// Round 16
// 529.931 us; speedup vs baseline: 1.3705x; 1.3705x over previous
//
#include <hip/hip_runtime.h>
#include <hip/hip_bf16.h>
#include <stdint.h>

typedef long long ll;
typedef float f32x4 __attribute__((ext_vector_type(4)));
typedef __bf16 bf16x8 __attribute__((ext_vector_type(8)));
typedef __bf16 bf16x4 __attribute__((ext_vector_type(4)));

// ---------------- merged weight prep + Xint zeroing ----------------
// blocks: [0,1024) conv-weight transpose; [1024,2560) W_trans^T split;
// [2560,3648) WcatT layer0 (KD=544); [3648,6720) WcatT layers1-3;
// [6720,8576) zero the 7.6MB Xint region.
__global__ void k_prep(const float* __restrict__ cr_w1, const float* __restrict__ cr_w2,
                       const float* __restrict__ cr_w3, __bf16* __restrict__ Wt1,
                       __bf16* __restrict__ Wt2, __bf16* __restrict__ Wt3,
                       const float* __restrict__ W_trans, __bf16* __restrict__ wth,
                       __bf16* __restrict__ wtl,
                       const float* __restrict__ Wrel0, const float* __restrict__ Wself0,
                       __bf16* __restrict__ wc0h, __bf16* __restrict__ wc0l,
                       const float* __restrict__ Wrel, const float* __restrict__ Wself,
                       __bf16* __restrict__ wc13h, __bf16* __restrict__ wc13l,
                       uint4* __restrict__ XintZ)
{
  __shared__ float t[32][33];
  int b = blockIdx.x; int tid = threadIdx.x;
  if (b < 1024){
    const float* w; __bf16* dst; int C, o;
    if (b < 256){ w=cr_w1; dst=Wt1; C=512; o=b; }
    else if (b < 512){ w=cr_w2; dst=Wt2; C=256; o=b-256; }
    else { w=cr_w3; dst=Wt3; C=256; o=b-512; }
    for (int c=tid; c<C; c+=256){
      const float* src = w + ((size_t)o*C + c)*25;
      float v[25];
      #pragma unroll
      for (int q=0;q<25;q++) v[q] = src[q];
      #pragma unroll
      for (int q=0;q<25;q++) dst[((size_t)o*25 + q)*C + c] = (__bf16)v[q];
    }
  } else if (b < 2560){
    ll idx = (ll)(b-1024)*256 + tid;  // over 768*512
    int r = (int)(idx % 768); int c = (int)(idx / 768);
    float x = W_trans[(ll)r*512 + c];
    __bf16 h = (__bf16)x;
    wth[idx] = h; wtl[idx] = (__bf16)(x - (float)h);
  } else if (b < 6720){
    int Din, Kpad, KD, bx, by;
    const float* wr; const float* ws2; __bf16* hb; __bf16* lb;
    if (b < 3648){
      int b2 = b-2560; bx = b2 % 68; by = b2/68; Din=532; Kpad=2176; KD=544;
      wr = Wrel0; ws2 = Wself0; hb = wc0h; lb = wc0l;
    } else {
      int b3 = b-3648; int l = b3/1024; int r2 = b3%1024; bx = r2%64; by = r2/64;
      Din=512; Kpad=2048; KD=512;
      wr = Wrel + (ll)l*3*512*512; ws2 = Wself + (ll)l*512*512;
      hb = wc13h + (ll)l*512*2048; lb = wc13l + (ll)l*512*2048;
    }
    int k0 = bx*32, o0 = by*32;
    int tx = tid&31, ty = tid>>5;
    for (int j=ty; j<32; j+=8){
      int k = k0 + j; float v = 0.f;
      int r = k / KD, d = k - r*KD;
      if (d < Din && r < 4)
        v = (r<3) ? wr[((ll)(r*Din+d))*512 + o0+tx] : ws2[(ll)d*512 + o0+tx];
      t[j][tx] = v;
    }
    __syncthreads();
    for (int j=ty; j<32; j+=8){
      float x = t[tx][j];
      __bf16 h = (__bf16)x;
      hb[(ll)(o0+j)*Kpad + k0+tx] = h;
      lb[(ll)(o0+j)*Kpad + k0+tx] = (__bf16)(x - (float)h);
    }
  } else {
    ll idx = (ll)(b-6720)*256 + tid;
    if (idx < 475136){
      uint4 z; z.x=0u; z.y=0u; z.z=0u; z.w=0u;
      XintZ[idx] = z;
    }
  }
}

// ---------------- MFMA GEMM ----------------
// A [M][K] fp32 (split in staging), B^T [N][K] pre-split bf16 (or virtual fmap).
// MODE 0: Cf = acc + biasN;  MODE 1: Cf = relu(acc);
// MODE 2: Cb^T = relu((acc+bM)*g+be) bf16;
// MODE 4: Xint[e][ch] = fm * sigmoid((acc+bM)*g+be + cbv), fm recomputed from Hf/Ec
// FMAPB=1: B[gn][k] = (Hf[i]+Ec[i])[k] * (Hf[j]+Ec[j])[k], i=gn/22, j=gn%22
template<int SPLIT, int MODE, int BN, int FMAPB>
__global__ __launch_bounds__(512) void gemm_mfma(
    const float* __restrict__ A,
    const __bf16* __restrict__ Bhi, const __bf16* __restrict__ Blo,
    float* __restrict__ Cf, __bf16* __restrict__ Cb,
    int M, int N, int K, ll sA, ll sB, ll sC,
    const float* __restrict__ biasN, const float* __restrict__ biasM,
    const float* __restrict__ gM, const float* __restrict__ beM,
    const float* __restrict__ Hf, const float* __restrict__ Ec,
    const float* __restrict__ CBV)
{
  constexpr int NF = BN/32;
  constexpr int SL = (4096 + BN*64) * (SPLIT?2:1);
  constexpr int REDB = 256*2*NF*16;
  constexpr int LDSB = (2*SL > REDB) ? 2*SL : REDB;
  __shared__ char lds[LDSB];

  int b = blockIdx.z;
  A += sA*b;
  if (!FMAPB){ Bhi += sB*b; if (SPLIT) Blo += sB*b; }

  const int tid = threadIdx.x;
  const int slice = tid>>8;
  const int tl = tid & 255;
  const int w4 = (tid>>6)&3;
  const int grp = tid>>8;
  const int l15 = tid&15, lg=(tid&63)>>4, lg16=lg*16;
  const int wave_m0=(w4>>1)*32, wave_n0=(w4&1)*(BN/2);
  const int m0 = blockIdx.y*64, n0 = blockIdx.x*BN;

  char* sA_H = lds + slice*SL;
  char* sB_H = sA_H + 4096;
  char* sA_L = sB_H + BN*64;
  char* sB_L = sA_L + 4096;

  const int sa_row=tl>>2, sa_c8=tl&3;
  const int sa_byte = sa_row*64 + ((sa_c8*16) ^ (((sa_row>>1)&3)<<4));
  const int gmA = m0 + sa_row;

  int baseA[2], baseB[NF];
  #pragma unroll
  for (int mf=0; mf<2; ++mf){
    int r = wave_m0 + mf*16 + l15;
    baseA[mf] = r*64 + (lg16 ^ (((r>>1)&3)<<4));
  }
  #pragma unroll
  for (int nf=0; nf<NF; ++nf){
    int r = wave_n0 + nf*16 + l15;
    baseB[nf] = r*64 + (lg16 ^ (((r>>1)&3)<<4));
  }

  f32x4 acc[2][NF] = {};

  for (int k0=0; k0<K; k0+=64){
    int kk = k0 + slice*32;
    __syncthreads();
    {
      float f[8] = {0,0,0,0,0,0,0,0};
      if (gmA < M){
        float4 p0 = *reinterpret_cast<const float4*>(A + (ll)gmA*K + kk + sa_c8*8);
        float4 p1 = *reinterpret_cast<const float4*>(A + (ll)gmA*K + kk + sa_c8*8 + 4);
        f[0]=p0.x; f[1]=p0.y; f[2]=p0.z; f[3]=p0.w;
        f[4]=p1.x; f[5]=p1.y; f[6]=p1.z; f[7]=p1.w;
      }
      bf16x8 h, l;
      #pragma unroll
      for (int j=0;j<8;j++){
        h[j] = (__bf16)f[j];
        if (SPLIT) l[j] = (__bf16)(f[j] - (float)h[j]);
      }
      *reinterpret_cast<bf16x8*>(sA_H + sa_byte) = h;
      if (SPLIT) *reinterpret_cast<bf16x8*>(sA_L + sa_byte) = l;
    }
    #pragma unroll
    for (int i=0;i<BN/64 || i<1;i++){
      int idx = tl + i*256;
      if (idx < BN*4){
        int row = idx>>2, c8 = idx&3;
        int gn = n0 + row;
        int byte = row*64 + ((c8*16) ^ (((row>>1)&3)<<4));
        if (FMAPB){
          bf16x8 v = {};
          if (gn < N){
            int pi = gn/22, pj = gn%22;
            const float* hi_ = Hf + ((ll)b*126+pi)*512 + kk + c8*8;
            const float* ei_ = Ec + ((ll)b*22 +pi)*512 + kk + c8*8;
            const float* hj_ = Hf + ((ll)b*126+pj)*512 + kk + c8*8;
            const float* ej_ = Ec + ((ll)b*22 +pj)*512 + kk + c8*8;
            float4 ha = *reinterpret_cast<const float4*>(hi_);
            float4 hb2 = *reinterpret_cast<const float4*>(hi_+4);
            float4 ea = *reinterpret_cast<const float4*>(ei_);
            float4 eb = *reinterpret_cast<const float4*>(ei_+4);
            float4 hc = *reinterpret_cast<const float4*>(hj_);
            float4 hd = *reinterpret_cast<const float4*>(hj_+4);
            float4 ec2 = *reinterpret_cast<const float4*>(ej_);
            float4 ed = *reinterpret_cast<const float4*>(ej_+4);
            float vi[8] = {ha.x+ea.x, ha.y+ea.y, ha.z+ea.z, ha.w+ea.w,
                           hb2.x+eb.x, hb2.y+eb.y, hb2.z+eb.z, hb2.w+eb.w};
            float vj[8] = {hc.x+ec2.x, hc.y+ec2.y, hc.z+ec2.z, hc.w+ec2.w,
                           hd.x+ed.x, hd.y+ed.y, hd.z+ed.z, hd.w+ed.w};
            #pragma unroll
            for (int q=0;q<8;q++) v[q] = (__bf16)(vi[q]*vj[q]);
          }
          *reinterpret_cast<bf16x8*>(sB_H + byte) = v;
        } else {
          bf16x8 v = {};
          if (gn < N) v = *reinterpret_cast<const bf16x8*>(Bhi + (ll)gn*K + kk + c8*8);
          *reinterpret_cast<bf16x8*>(sB_H + byte) = v;
          if (SPLIT){
            bf16x8 vl = {};
            if (gn < N) vl = *reinterpret_cast<const bf16x8*>(Blo + (ll)gn*K + kk + c8*8);
            *reinterpret_cast<bf16x8*>(sB_L + byte) = vl;
          }
        }
      }
    }
    __syncthreads();
    bf16x8 aH[2], bH[NF];
    #pragma unroll
    for (int mf=0; mf<2; ++mf) aH[mf] = *reinterpret_cast<const bf16x8*>(sA_H + baseA[mf]);
    #pragma unroll
    for (int nf=0; nf<NF; ++nf) bH[nf] = *reinterpret_cast<const bf16x8*>(sB_H + baseB[nf]);
    if (SPLIT){
      bf16x8 aL[2], bL[NF];
      #pragma unroll
      for (int mf=0; mf<2; ++mf) aL[mf] = *reinterpret_cast<const bf16x8*>(sA_L + baseA[mf]);
      #pragma unroll
      for (int nf=0; nf<NF; ++nf) bL[nf] = *reinterpret_cast<const bf16x8*>(sB_L + baseB[nf]);
      #pragma unroll
      for (int mf=0; mf<2; ++mf)
        #pragma unroll
        for (int nf=0; nf<NF; ++nf){
          acc[mf][nf] = __builtin_amdgcn_mfma_f32_16x16x32_bf16(aH[mf], bH[nf], acc[mf][nf], 0,0,0);
          acc[mf][nf] = __builtin_amdgcn_mfma_f32_16x16x32_bf16(aH[mf], bL[nf], acc[mf][nf], 0,0,0);
          acc[mf][nf] = __builtin_amdgcn_mfma_f32_16x16x32_bf16(aL[mf], bH[nf], acc[mf][nf], 0,0,0);
        }
    } else {
      #pragma unroll
      for (int mf=0; mf<2; ++mf)
        #pragma unroll
        for (int nf=0; nf<NF; ++nf)
          acc[mf][nf] = __builtin_amdgcn_mfma_f32_16x16x32_bf16(aH[mf], bH[nf], acc[mf][nf], 0,0,0);
    }
  }

  __syncthreads();
  if (grp==1){
    char* rp = lds + (ll)(tid-256)*(2*NF*16);
    #pragma unroll
    for (int mf=0; mf<2; ++mf)
      #pragma unroll
      for (int nf=0; nf<NF; ++nf)
        *reinterpret_cast<f32x4*>(rp + (mf*NF+nf)*16) = acc[mf][nf];
  }
  __syncthreads();
  if (grp!=0) return;
  {
    char* rp = lds + (ll)tid*(2*NF*16);
    #pragma unroll
    for (int mf=0; mf<2; ++mf)
      #pragma unroll
      for (int nf=0; nf<NF; ++nf)
        acc[mf][nf] += *reinterpret_cast<f32x4*>(rp + (mf*NF+nf)*16);
  }

  if (MODE==0 || MODE==1){
    float* C = Cf + sC*b;
    #pragma unroll
    for (int mf=0; mf<2; ++mf){
      int gmb = m0 + wave_m0 + mf*16 + lg*4;
      #pragma unroll
      for (int nf=0; nf<NF; ++nf){
        int gn = n0 + wave_n0 + nf*16 + l15;
        if (gn >= N) continue;
        float bn_ = (MODE==0 && biasN) ? biasN[gn] : 0.f;
        f32x4 a = acc[mf][nf];
        #pragma unroll
        for (int r=0;r<4;r++){
          int gm = gmb + r;
          if (gm < M){
            float v = a[r] + bn_;
            if (MODE==1) v = fmaxf(v, 0.f);
            C[(ll)gm*N + gn] = v;
          }
        }
      }
    }
  } else if (MODE==2){
    __bf16* C = Cb + sC*b;
    #pragma unroll
    for (int mf=0; mf<2; ++mf){
      int gmb = m0 + wave_m0 + mf*16 + lg*4;
      float b0=biasM[gmb], b1=biasM[gmb+1], b2=biasM[gmb+2], b3=biasM[gmb+3];
      float g0=gM[gmb], g1=gM[gmb+1], g2=gM[gmb+2], g3=gM[gmb+3];
      float e0=beM[gmb], e1=beM[gmb+1], e2=beM[gmb+2], e3=beM[gmb+3];
      #pragma unroll
      for (int nf=0; nf<NF; ++nf){
        int gn = n0 + wave_n0 + nf*16 + l15;
        if (gn >= N) continue;
        f32x4 a = acc[mf][nf];
        union { bf16x4 v; uint2 u; } pk;
        pk.v[0] = (__bf16)fmaxf((a[0]+b0)*g0+e0, 0.f);
        pk.v[1] = (__bf16)fmaxf((a[1]+b1)*g1+e1, 0.f);
        pk.v[2] = (__bf16)fmaxf((a[2]+b2)*g2+e2, 0.f);
        pk.v[3] = (__bf16)fmaxf((a[3]+b3)*g3+e3, 0.f);
        *reinterpret_cast<uint2*>(C + (ll)gn*M + gmb) = pk.u;
      }
    }
  } else { // MODE 4
    __bf16* C = Cb + sC*b;
    const float* cb = CBV + (ll)b*512;
    #pragma unroll
    for (int mf=0; mf<2; ++mf){
      int gmb = m0 + wave_m0 + mf*16 + lg*4;
      float b0=biasM[gmb], b1=biasM[gmb+1], b2=biasM[gmb+2], b3=biasM[gmb+3];
      float g0=gM[gmb], g1=gM[gmb+1], g2=gM[gmb+2], g3=gM[gmb+3];
      float e0=beM[gmb], e1=beM[gmb+1], e2=beM[gmb+2], e3=beM[gmb+3];
      float c0=cb[gmb], c1=cb[gmb+1], c2=cb[gmb+2], c3=cb[gmb+3];
      #pragma unroll
      for (int nf=0; nf<NF; ++nf){
        int gn = n0 + wave_n0 + nf*16 + l15;
        if (gn >= N) continue;
        f32x4 a = acc[mf][nf];
        int pi = gn/22, pj = gn%22;
        float4 hi4 = *reinterpret_cast<const float4*>(Hf + ((ll)b*126+pi)*512 + gmb);
        float4 ei4 = *reinterpret_cast<const float4*>(Ec + ((ll)b*22 +pi)*512 + gmb);
        float4 hj4 = *reinterpret_cast<const float4*>(Hf + ((ll)b*126+pj)*512 + gmb);
        float4 ej4 = *reinterpret_cast<const float4*>(Ec + ((ll)b*22 +pj)*512 + gmb);
        float fm0 = (hi4.x+ei4.x)*(hj4.x+ej4.x);
        float fm1 = (hi4.y+ei4.y)*(hj4.y+ej4.y);
        float fm2 = (hi4.z+ei4.z)*(hj4.z+ej4.z);
        float fm3 = (hi4.w+ei4.w)*(hj4.w+ej4.w);
        float s0 = (a[0]+b0)*g0+e0 + c0;
        float s1 = (a[1]+b1)*g1+e1 + c1;
        float s2 = (a[2]+b2)*g2+e2 + c2;
        float s3 = (a[3]+b3)*g3+e3 + c3;
        union { bf16x4 v; uint2 u; } pk;
        pk.v[0] = (__bf16)(fm0 / (1.f + expf(-s0)));
        pk.v[1] = (__bf16)(fm1 / (1.f + expf(-s1)));
        pk.v[2] = (__bf16)(fm2 / (1.f + expf(-s2)));
        pk.v[3] = (__bf16)(fm3 / (1.f + expf(-s3)));
        int py = gn/22, px = gn%22;
        int e = (py+2)*32 + px + 2;
        *reinterpret_cast<uint2*>(C + (ll)e*512 + gmb) = pk.u;
      }
    }
  }
}

// ---------------- MFMA bf16 5x5 conv (verified LDS-staged) ----------------
template<int CIN, int OCHT, bool FINAL>
__global__ __launch_bounds__(256) void conv5_mfma(
    const __bf16* __restrict__ Xg, const __bf16* __restrict__ Wt,
    const float* __restrict__ bias, __bf16* __restrict__ Xout,
    float* __restrict__ outF)
{
  __shared__ bf16x8 Xs8[272*32/8];
  __shared__ bf16x8 Ws8[5*64*32/8];
  char* xs = (char*)Xs8;
  char* wsm = (char*)Ws8;

  const int tid = threadIdx.x;
  const int l = tid & 63;
  const int l15 = l & 15, lg = l >> 4, lg16 = (l>>4)*16;
  const int w = tid >> 6;
  const int wave_o0 = (w>>1)*32;
  const int wave_p0 = (w&1)*64;
  const int b = blockIdx.z;
  const int p0 = blockIdx.x*128;
  const int o0 = blockIdx.y*64;

  int orow0 = wave_o0 + l15;
  int orow1 = wave_o0 + 16 + l15;
  int baseA0 = orow0*64 + (lg16 ^ (((orow0>>1)&3)<<4));
  int baseA1 = orow1*64 + (lg16 ^ (((orow1>>1)&3)<<4));
  int pl[4];
  #pragma unroll
  for (int pf=0; pf<4; ++pf) pl[pf] = wave_p0 + pf*16 + l15;

  f32x4 acc[2][4] = {};

  const int NCB = CIN/32;
  for (int cblk=0; cblk<NCB; ++cblk){
    __syncthreads();
    #pragma unroll
    for (int i=0;i<5;i++){
      int idx = tid + i*256;
      if (idx < 1088){
        int e = idx>>2, c8 = idx&3;
        const __bf16* g = Xg + ((size_t)(b*928 + p0 + e))*CIN + cblk*32 + c8*8;
        bf16x8 v = *reinterpret_cast<const bf16x8*>(g);
        int byte = e*64 + ((c8*16) ^ (((e>>1)&3)<<4));
        *reinterpret_cast<bf16x8*>(xs + byte) = v;
      }
    }
    for (int g5=0; g5<5; ++g5){
      if (g5>0) __syncthreads();
      #pragma unroll
      for (int i=0;i<5;i++){
        int idx = tid + i*256;
        int tapL = idx>>8, r = idx&255;
        int o = r>>2, c8 = r&3;
        const __bf16* g = Wt + ((size_t)(o0+o)*25 + (g5*5+tapL))*CIN + cblk*32 + c8*8;
        bf16x8 v = *reinterpret_cast<const bf16x8*>(g);
        int byte = tapL*4096 + o*64 + ((c8*16) ^ (((o>>1)&3)<<4));
        *reinterpret_cast<bf16x8*>(wsm + byte) = v;
      }
      __syncthreads();
      #pragma unroll
      for (int tapL=0; tapL<5; ++tapL){
        bf16x8 a0 = *reinterpret_cast<const bf16x8*>(wsm + tapL*4096 + baseA0);
        bf16x8 a1 = *reinterpret_cast<const bf16x8*>(wsm + tapL*4096 + baseA1);
        int koff = g5*32 + tapL;
        #pragma unroll
        for (int pf=0; pf<4; ++pf){
          int e = pl[pf] + koff;
          bf16x8 bv = *reinterpret_cast<const bf16x8*>(xs + e*64 + (lg16 ^ (((e>>1)&3)<<4)));
          acc[0][pf] = __builtin_amdgcn_mfma_f32_16x16x32_bf16(a0, bv, acc[0][pf], 0,0,0);
          acc[1][pf] = __builtin_amdgcn_mfma_f32_16x16x32_bf16(a1, bv, acc[1][pf], 0,0,0);
        }
      }
    }
  }

  #pragma unroll
  for (int of=0; of<2; ++of){
    int og = o0 + wave_o0 + of*16 + lg*4;
    float b0 = bias[og], b1 = bias[og+1], b2 = bias[og+2], b3 = bias[og+3];
    #pragma unroll
    for (int pf=0; pf<4; ++pf){
      int p = p0 + pl[pf];
      int py = p>>5, px = p&31;
      if (py>=22 || px>=22) continue;
      f32x4 a = acc[of][pf];
      float v0 = fmaxf(a[0]+b0, 0.f), v1 = fmaxf(a[1]+b1, 0.f);
      float v2 = fmaxf(a[2]+b2, 0.f), v3 = fmaxf(a[3]+b3, 0.f);
      if (FINAL){
        size_t base = ((size_t)b*OCHT + og)*484 + py*22 + px;
        outF[base] = v0; outF[base+484] = v1; outF[base+968] = v2; outF[base+1452] = v3;
      } else {
        union { bf16x4 v; uint2 u; } pk;
        pk.v[0] = (__bf16)v0; pk.v[1] = (__bf16)v1; pk.v[2] = (__bf16)v2; pk.v[3] = (__bf16)v3;
        int e = p + 66;
        *reinterpret_cast<uint2*>(Xout + ((size_t)(b*928 + e))*OCHT + og) = pk.u;
      }
    }
  }
}

// ---------------- merged gather: nodes + ea + seqT ----------------
// blocks: [0,88) ent, [88,152) link, [152,192) tfeat, [192,280) ea, [280,2328) seqT
__global__ void k_gather(const float* __restrict__ seq, const float* __restrict__ att,
                         const int* __restrict__ midx, const int* __restrict__ ls_,
                         const float* __restrict__ te, float* __restrict__ h0,
                         float* __restrict__ ea, __bf16* __restrict__ sqTh,
                         __bf16* __restrict__ sqTl)
{
  __shared__ float part[32][8];
  __shared__ float wv[32];
  __shared__ float vals[1024];
  __shared__ float red[256];
  __shared__ float tt2[32][33];
  int b = blockIdx.x; int t = threadIdx.x;
  if (b < 88){
    int n = b/22, e = b%22;
    int rows[4];
    #pragma unroll
    for (int m=0;m<4;m++) rows[m] = midx[(n*22+e)*4+m];
    for (int d=t; d<512; d+=256){
      float v[4]; float mx = -1e30f;
      #pragma unroll
      for (int m=0;m<4;m++){
        v[m] = seq[((ll)n*1024+rows[m])*512 + d];
        h0[((ll)n*126+22+e*4+m)*532 + d] = v[m];
        mx = fmaxf(mx, v[m]);
      }
      float s = 0.f;
      #pragma unroll
      for (int m=0;m<4;m++) s += expf(v[m]-mx);
      h0[((ll)n*126+e)*532 + d] = mx + logf(s);
    }
  } else if (b < 152){
    int bb = b-88;
    int n = bb/16, l = bb%16;
    int ls = ls_[n*16+l];
    int tt = t>>3, lane = t&7;
    float acc = 0.f;
    for (int i=lane; i<384; i+=8){
      int h = i>>5, s = i&31;
      acc += att[((ll)(n*12+h)*1024 + ls+s)*1024 + (ls+tt)];
    }
    part[tt][lane] = acc; __syncthreads();
    if (lane==0){
      float s2=0.f;
      #pragma unroll
      for (int q=0;q<8;q++) s2 += part[tt][q];
      wv[tt] = s2*(1.f/12.f);
    }
    __syncthreads();
    for (int d=t; d<512; d+=256){
      float a2 = 0.f;
      for (int tk=0;tk<32;tk++) a2 += wv[tk]*seq[((ll)n*1024+ls+tk)*512 + d];
      h0[((ll)n*126+110+l)*532 + d] = a2*(1.f/32.f);
    }
  } else if (b < 192){
    int idx = (b-152)*256 + t;
    if (idx < 4*126*20){
      int q = idx%20; int i = (idx/20)%126; int n = idx/(20*126);
      int ty = (i<22)?0:((i<110)?1:2);
      h0[((ll)n*126+i)*532 + 512 + q] = te[ty*20+q];
    }
  } else if (b < 280){
    int bb = b-192;
    int n = bb/22, e = bb%22;
    int rows[4];
    #pragma unroll
    for (int m=0;m<4;m++) rows[m] = midx[(n*22+e)*4+m];
    float local = 0.f;
    for (int c=t; c<1024; c+=256){
      float acc = 0.f;
      #pragma unroll
      for (int m=0;m<4;m++){
        const float* base = att + ((ll)n*12*1024 + rows[m])*1024 + c;
        #pragma unroll
        for (int h=0;h<12;h++) acc += base[(ll)h*1048576];
      }
      acc *= (1.f/48.f);
      vals[c] = acc; local += acc;
    }
    red[t] = local; __syncthreads();
    for (int s=128;s>0;s>>=1){ if (t<s) red[t]+=red[t+s]; __syncthreads(); }
    float denom = red[0] + 1e-5f;
    for (int c=t; c<1024; c+=256) ea[((ll)bb)*1024 + c] = vals[c]/denom;
  } else {
    int b2 = b-280;
    int n = b2>>9; int rem = b2&511;
    int r0 = (rem&31)*32, c0 = (rem>>5)*32;
    int tx = t&31, ty = t>>5;
    for (int j=ty; j<32; j+=8)
      tt2[j][tx] = seq[((ll)n*1024 + r0+j)*512 + c0+tx];
    __syncthreads();
    for (int j=ty; j<32; j+=8){
      float x = tt2[tx][j];
      __bf16 h = (__bf16)x;
      ll o = ((ll)n*512 + c0+j)*1024 + r0+tx;
      sqTh[o] = h; sqTl[o] = (__bf16)(x - (float)h);
    }
  }
}

// ---------------- sparse RGCN buildX (coalesced, per-relation KD layout) ----------------
__global__ void k_buildX_s(const float* __restrict__ h, float* __restrict__ X,
                           int Din, int KD){
  int n = blockIdx.x/126, i = blockIdx.x%126;
  const float* hb = h + (ll)n*126*Din;
  ll rowoff = (ll)(n*126+i)*4*KD;
  const float inv1 = 1.f/(1.f+1e-5f), inv3 = 1.f/(3.f+1e-5f), inv4 = 1.f/(4.f+1e-5f);
  for (int d=threadIdx.x; d<KD; d+=256){
    float m0v=0.f, m1v=0.f, m2v=0.f, hh=0.f;
    if (d < Din){
      if (i < 22){
        int base = 22 + i*4;
        float s = hb[(ll)(base+0)*Din+d] + hb[(ll)(base+1)*Din+d]
                + hb[(ll)(base+2)*Din+d] + hb[(ll)(base+3)*Din+d];
        m0v = s * inv4;
      } else if (i < 110){
        int em = i-22, e = em>>2, base = 22+(e<<2);
        m0v = hb[(ll)e*Din+d] * inv1;
        float s1 = 0.f;
        #pragma unroll
        for (int m2=0;m2<4;m2++) if (base+m2 != i) s1 += hb[(ll)(base+m2)*Din+d];
        m1v = s1 * inv3;
        m2v = hb[(ll)(110+(em&15))*Din+d] * inv1;
      } else {
        int li0 = i-110;
        int cnt = (li0<8)?6:5;
        float s = 0.f;
        for (int t2=0;t2<cnt;t2++) s += hb[(ll)(22+li0+16*t2)*Din+d];
        m2v = s / ((float)cnt + 1e-5f);
      }
      hh = hb[(ll)i*Din+d];
    }
    X[rowoff + 0*KD + d] = m0v;
    X[rowoff + 1*KD + d] = m1v;
    X[rowoff + 2*KD + d] = m2v;
    X[rowoff + 3*KD + d] = hh;
  }
}

// ---------------- pooled channel-SE MLP ----------------
__global__ void k_poolcb(const float* __restrict__ hfin, const float* __restrict__ ectx,
                         const float* __restrict__ w1, const float* __restrict__ b1,
                         const float* __restrict__ g1, const float* __restrict__ be1,
                         const float* __restrict__ w2, const float* __restrict__ b2,
                         const float* __restrict__ g2, const float* __restrict__ be2,
                         float* __restrict__ cb){
  __shared__ float ps[512], t1[256];
  int n = blockIdx.x; int t = threadIdx.x;
  for (int c=t; c<512; c+=256){
    float s = 0.f;
    for (int i=0;i<22;i++)
      s += hfin[((ll)n*126+i)*512 + c] + ectx[((ll)n*22+i)*512 + c];
    ps[c] = s*s*(1.f/484.f);
  }
  __syncthreads();
  {
    float acc = 0.f;
    for (int c=0;c<512;c++) acc += w1[t*512+c]*ps[c];
    float v = g1[t]*(acc+b1[t]) + be1[t];
    t1[t] = fmaxf(v, 0.f);
  }
  __syncthreads();
  for (int o=t; o<512; o+=256){
    float acc = 0.f;
    for (int c=0;c<256;c++) acc += w2[o*256+c]*t1[c];
    cb[n*512+o] = g2[o]*(acc+b2[o]) + be2[o];
  }
}

// ---------------- launcher ----------------
extern "C" void kernel_launch(void* const* d_in, const int* in_sizes, int n_in,
                              void* d_out, int out_size, void* d_ws, size_t ws_size,
                              hipStream_t stream)
{
  (void)in_sizes; (void)n_in; (void)out_size; (void)ws_size;
  const float* seqout   = (const float*)d_in[0];
  const float* att      = (const float*)d_in[1];
  const float* W_trans  = (const float*)d_in[2];
  const float* b_trans  = (const float*)d_in[3];
  const float* type_emb = (const float*)d_in[4];
  const float* Wrel0    = (const float*)d_in[5];
  const float* Wself0   = (const float*)d_in[6];
  const float* Wrel     = (const float*)d_in[7];
  const float* Wself    = (const float*)d_in[8];
  const float* fs_w1    = (const float*)d_in[9];
  const float* fs_b1    = (const float*)d_in[10];
  const float* fs_g1    = (const float*)d_in[11];
  const float* fs_be1   = (const float*)d_in[12];
  const float* fs_w2    = (const float*)d_in[13];
  const float* fs_b2    = (const float*)d_in[14];
  const float* fs_g2    = (const float*)d_in[15];
  const float* fs_be2   = (const float*)d_in[16];
  const float* fc_w1    = (const float*)d_in[17];
  const float* fc_b1    = (const float*)d_in[18];
  const float* fc_g1    = (const float*)d_in[19];
  const float* fc_be1   = (const float*)d_in[20];
  const float* fc_w2    = (const float*)d_in[21];
  const float* fc_b2    = (const float*)d_in[22];
  const float* fc_g2    = (const float*)d_in[23];
  const float* fc_be2   = (const float*)d_in[24];
  const float* cr_w1    = (const float*)d_in[25];
  const float* cr_b1    = (const float*)d_in[26];
  const float* cr_w2    = (const float*)d_in[27];
  const float* cr_b2    = (const float*)d_in[28];
  const float* cr_w3    = (const float*)d_in[29];
  const float* cr_b3    = (const float*)d_in[30];
  const int*   midx     = (const int*)d_in[31];
  const int*   lstart   = (const int*)d_in[32];
  float* out            = (float*)d_out;

  char* wsb = (char*)d_ws;
  size_t off = 0;
  auto allocB = [&](size_t nbytes)->char*{ char* p = wsb + off; off += (nbytes + 63) & ~(size_t)63; return p; };
  float* seq   = (float*)allocB((size_t)4096*512*4);
  float* h0    = (float*)allocB((size_t)504*532*4);
  float* ea    = (float*)allocB((size_t)88*1024*4);
  float* ectx  = (float*)allocB((size_t)88*512*4);
  float* X     = (float*)allocB((size_t)504*2176*4);
  float* hA    = (float*)allocB((size_t)504*512*4);
  float* hB    = (float*)allocB((size_t)504*512*4);
  float* cbv   = (float*)allocB(2048*4);
  __bf16* wth  = (__bf16*)allocB((size_t)512*768*2);
  __bf16* wtl  = (__bf16*)allocB((size_t)512*768*2);
  __bf16* sqTh = (__bf16*)allocB((size_t)4*512*1024*2);
  __bf16* sqTl = (__bf16*)allocB((size_t)4*512*1024*2);
  __bf16* wc0h = (__bf16*)allocB((size_t)512*2176*2);
  __bf16* wc0l = (__bf16*)allocB((size_t)512*2176*2);
  __bf16* wc13h= (__bf16*)allocB((size_t)3*512*2048*2);
  __bf16* wc13l= (__bf16*)allocB((size_t)3*512*2048*2);
  __bf16* s1bT = (__bf16*)allocB((size_t)4*484*256*2);
  __bf16* Xint1 = (__bf16*)allocB((size_t)4*928*512*2);
  __bf16* Xint2 = (__bf16*)allocB((size_t)4*928*256*2);
  __bf16* Xint3 = (__bf16*)allocB((size_t)4*928*256*2);
  __bf16* Wt1   = (__bf16*)allocB((size_t)256*25*512*2);
  __bf16* Wt2   = (__bf16*)allocB((size_t)256*25*256*2);
  __bf16* Wt3   = (__bf16*)allocB((size_t)512*25*256*2);

  // weight prep + Xint zeroing, one dispatch
  k_prep<<<8576,256,0,stream>>>(cr_w1, cr_w2, cr_w3, Wt1, Wt2, Wt3,
                                W_trans, wth, wtl,
                                Wrel0, Wself0, wc0h, wc0l,
                                Wrel, Wself, wc13h, wc13l,
                                reinterpret_cast<uint4*>(Xint1));

  // seq = seqout @ W_trans + b_trans
  gemm_mfma<1,0,128,0><<<dim3(4,64,1),512,0,stream>>>(seqout, wth, wtl, seq, nullptr,
      4096,512,768, 0,0,0, b_trans,nullptr,nullptr,nullptr, nullptr,nullptr,nullptr);
  // node features + ea + seqT (one dispatch)
  k_gather<<<2328,256,0,stream>>>(seq, att, midx, lstart, type_emb, h0, ea, sqTh, sqTl);
  // e_ctx = ea @ seq
  gemm_mfma<1,0,64,0><<<dim3(8,1,4),512,0,stream>>>(ea, sqTh, sqTl, ectx, nullptr,
      22,512,1024, (ll)22*1024, (ll)512*1024, (ll)22*512,
      nullptr,nullptr,nullptr,nullptr, nullptr,nullptr,nullptr);
  // RGCN layer 0 (Din=532, KD=544, K=2176)
  k_buildX_s<<<504,256,0,stream>>>(h0, X, 532, 544);
  gemm_mfma<1,1,64,0><<<dim3(8,8,1),512,0,stream>>>(X, wc0h, wc0l, hA, nullptr,
      504,512,2176, 0,0,0, nullptr,nullptr,nullptr,nullptr, nullptr,nullptr,nullptr);
  // RGCN layers 1..3 (Din=512, KD=512, K=2048)
  float* hcur = hA; float* hnxt = hB;
  for (int l=0;l<3;l++){
    k_buildX_s<<<504,256,0,stream>>>(hcur, X, 512, 512);
    gemm_mfma<1,1,64,0><<<dim3(8,8,1),512,0,stream>>>(X,
        wc13h + (ll)l*512*2048, wc13l + (ll)l*512*2048, hnxt, nullptr,
        504,512,2048, 0,0,0, nullptr,nullptr,nullptr,nullptr, nullptr,nullptr,nullptr);
    float* t = hcur; hcur = hnxt; hnxt = t;
  }
  // pooled channel-SE MLP
  k_poolcb<<<4,256,0,stream>>>(hcur, ectx, fc_w1, fc_b1, fc_g1, fc_be1,
                               fc_w2, fc_b2, fc_g2, fc_be2, cbv);
  // SE spatial 1 (B = virtual fmap from hcur/ectx)
  gemm_mfma<0,2,64,1><<<dim3(8,4,4),512,0,stream>>>(fs_w1, nullptr, nullptr, nullptr, s1bT,
      256,484,512, 0, 0, (ll)484*256,
      nullptr, fs_b1, fs_g1, fs_be1, hcur, ectx, nullptr);
  // SE spatial 2 fused gate -> Xint1
  gemm_mfma<0,4,64,0><<<dim3(8,8,4),512,0,stream>>>(fs_w2, s1bT, nullptr, nullptr, Xint1,
      512,484,256, 0, (ll)484*256, (ll)928*512,
      nullptr, fs_b2, fs_g2, fs_be2, hcur, ectx, cbv);
  // conv stack
  conv5_mfma<512,256,false><<<dim3(6,4,4),256,0,stream>>>(Xint1, Wt1, cr_b1, Xint2, nullptr);
  conv5_mfma<256,256,false><<<dim3(6,4,4),256,0,stream>>>(Xint2, Wt2, cr_b2, Xint3, nullptr);
  conv5_mfma<256,512,true ><<<dim3(6,8,4),256,0,stream>>>(Xint3, Wt3, cr_b3, nullptr, out);
}